// Round 16
// baseline (714.901 us; speedup 1.0000x reference)
//
#include <hip/hip_runtime.h>
#include <hip/hip_bf16.h>

#define N_NODES 10000
#define N_EDGES 160000
#define DIM     128
#define NBASIS  16
#define LDT     136   // LDS row stride (bf16); 272B row, 16B aligned

typedef __bf16 bf16x8 __attribute__((ext_vector_type(8)));
typedef __bf16 bf16x4 __attribute__((ext_vector_type(4)));
typedef __bf16 bf16x2 __attribute__((ext_vector_type(2)));
typedef float  f32x4  __attribute__((ext_vector_type(4)));

__device__ __forceinline__ float silu_f(float x){
  return x * (1.0f / (1.0f + __expf(-x)));
}
__device__ __forceinline__ f32x4 mfma16(bf16x8 a, bf16x8 b, f32x4 c){
  return __builtin_amdgcn_mfma_f32_16x16x32_bf16(a,b,c,0,0,0);
}

// Swizzled weight layout: frag (kc,ni,lane) at Wz[(kc*512+ni*64+lane)*8+j].
// Design log: r9 LDS weights 140->90; r10 operand-swap 90->81; r11 fused
// mij+segsum 728->663; r12 reg radW 663->622; r13 node-MLP merge 622->550;
// r14 fat small blocks REGRESSED; r15 barrier reorder ~neutral (545);
// r16: ef/ephi never hit HBM -- segment-reduced INSIDE mlp_layer via LDS +
// per-run fp32 atomics (mij_segsum trick); node_update becomes elementwise.
// r8 lesson: smaller edge tiles double chip-wide weight traffic.
// r6 lesson: never force min-waves that cap VGPR below live state.

struct WPtrs { const float* p[11]; };

// ===========================================================================
// Combined per-layer MLP dispatch.
//  blocks [0, nodeB):   R- and u-MLPs on xi (64 rows/block, 4 indep waves)
//  blocks [nodeB, ...): edge MLPs on mij (128 edges/block) + in-kernel
//                       segment reduction of ef*dir -> fi, ephi -> phi.
// ===========================================================================
template<bool WITH_R>
__global__ __launch_bounds__(256,3) void mlp_layer(
    int nodeB,
    const __bf16* __restrict__ mij,
    const int*    __restrict__ esrc, const float* __restrict__ dirv,
    const __bf16* __restrict__ fW1z, const float* __restrict__ fb1,
    const __bf16* __restrict__ fW2z, const float* __restrict__ fb2,
    const __bf16* __restrict__ FW1z, const float* __restrict__ Fb1,
    const float*  __restrict__ FW2v, const float* __restrict__ Fb2,
    const __bf16* __restrict__ rW1z, const float* __restrict__ rb1,
    const __bf16* __restrict__ rW2z, const float* __restrict__ rb2,
    const float*  __restrict__ swv,
    float* __restrict__ fiG, float* __restrict__ phiG,
    const float* __restrict__ X,
    const __bf16* __restrict__ RW1z, const float* __restrict__ Rb1,
    const __bf16* __restrict__ RW2z, const float* __restrict__ Rb2,
    const __bf16* __restrict__ uW1z, const float* __restrict__ ub1,
    const __bf16* __restrict__ uW2z, const float* __restrict__ ub2,
    float* __restrict__ Rv, float* __restrict__ uv)
{
  __shared__ __bf16 sH[128*LDT];   // 34816 B
  __shared__ __bf16 sW[8192];      // 16384 B
  __shared__ int    sE[128];       //   512 B
  __shared__ float  sDir[128*3];   //  1536 B   (total 53248 -> 3 blocks/CU)
  const int tid=threadIdx.x, lane=tid&63, wv=tid>>6, l15=lane&15, quad=lane>>4;

  if ((int)blockIdx.x < nodeB){
    // ---------------- node path: R and u MLPs, 16 rows per wave -----------
    const long row0n = (long)blockIdx.x*64 + wv*16;
    const long rA = row0n + l15;
    const bool okA = rA < N_NODES;

    bf16x8 fa[4];
    #pragma unroll
    for (int kc=0;kc<4;kc++){
      int kb=kc*32+quad*8;
      bf16x8 a;
      #pragma unroll
      for (int i=0;i<8;i++) a[i]=(__bf16)0.f;
      if (okA){
        float4 u0 = *(const float4*)(X + rA*DIM + kb);
        float4 u1 = *(const float4*)(X + rA*DIM + kb + 4);
        a[0]=(__bf16)u0.x;a[1]=(__bf16)u0.y;a[2]=(__bf16)u0.z;a[3]=(__bf16)u0.w;
        a[4]=(__bf16)u1.x;a[5]=(__bf16)u1.y;a[6]=(__bf16)u1.z;a[7]=(__bf16)u1.w;
      }
      fa[kc]=a;
    }

    f32x4 acc[8];
    auto zacc = [&](){
      #pragma unroll
      for (int ni=0;ni<8;++ni) acc[ni]=(f32x4){0.f,0.f,0.f,0.f};
    };
    auto gemmA = [&](const __bf16* __restrict__ Wz){
      #pragma unroll
      for (int kc=0;kc<4;kc++){
        #pragma unroll
        for (int ni=0;ni<8;ni++){
          bf16x8 w = *(const bf16x8*)(Wz + (long)(kc*512 + ni*64 + lane)*8);
          acc[ni]=mfma16(w,fa[kc],acc[ni]);
        }
      }
    };
    auto gemmH = [&](const __bf16* __restrict__ Wz){
      #pragma unroll
      for (int kc=0;kc<4;kc++){
        bf16x8 h0=*(bf16x8*)&sH[(wv*16+l15)*LDT + kc*32 + quad*8];
        #pragma unroll
        for (int ni=0;ni<8;ni++){
          bf16x8 w = *(const bf16x8*)(Wz + (long)(kc*512 + ni*64 + lane)*8);
          acc[ni]=mfma16(w,h0,acc[ni]);
        }
      }
    };
    auto hEpi = [&](const float* __restrict__ b1){
      #pragma unroll
      for (int ni=0;ni<8;++ni){
        int n0 = ni*16 + quad*4;
        float4 bb = *(const float4*)(b1 + n0);
        bf16x4 h;
        h[0]=(__bf16)silu_f(acc[ni][0]+bb.x);
        h[1]=(__bf16)silu_f(acc[ni][1]+bb.y);
        h[2]=(__bf16)silu_f(acc[ni][2]+bb.z);
        h[3]=(__bf16)silu_f(acc[ni][3]+bb.w);
        *(bf16x4*)&sH[(wv*16+l15)*LDT + n0] = h;
      }
    };
    auto cStoreF = [&](const float* __restrict__ b2, float* __restrict__ Y){
      if (okA){
        #pragma unroll
        for (int ni=0;ni<8;++ni){
          int n0 = ni*16 + quad*4;
          float4 bb = *(const float4*)(b2 + n0);
          float4 o;
          o.x=acc[ni][0]+bb.x; o.y=acc[ni][1]+bb.y;
          o.z=acc[ni][2]+bb.z; o.w=acc[ni][3]+bb.w;
          *(float4*)(Y + rA*DIM + n0) = o;
        }
      }
    };

    zacc(); gemmA(RW1z); hEpi(Rb1);
    zacc(); gemmH(RW2z); cStoreF(Rb2, Rv);
    zacc(); gemmA(uW1z); hEpi(ub1);
    zacc(); gemmH(uW2z); cStoreF(ub2, uv);
    return;
  }

  // ---------------- edge path: F/f[/r] MLPs on mij ------------------------
  const long row0 = (long)(blockIdx.x - nodeB)*128;
  const int  rloc0 = wv*32 + l15;
  const long rB0 = row0 + rloc0, rB1 = rB0+16;

  // stage esrc + dir for this block's 128 edges
  if (tid < 32)  *(int4*)&sE[tid*4]    = *(const int4*)(esrc + row0 + tid*4);
  if (tid >= 64 && tid < 160)
    *(float4*)&sDir[(tid-64)*4] = *(const float4*)(dirv + row0*3 + (tid-64)*4);

  bf16x8 fb[2][4];
  #pragma unroll
  for (int kc=0;kc<4;kc++){
    fb[0][kc] = *(const bf16x8*)(mij + rB0*DIM + kc*32 + quad*8);
    fb[1][kc] = *(const bf16x8*)(mij + rB1*DIM + kc*32 + quad*8);
  }
  float swr[2];
  if constexpr (WITH_R){ swr[0]=swv[rB0]; swr[1]=swv[rB1]; }

  f32x4 acc[2][8];
  bf16x8 pre[4];
  float eF[2];

  auto preload = [&](const __bf16* __restrict__ Wz, int half){
    #pragma unroll
    for (int it=0; it<4; ++it)
      pre[it] = *(const bf16x8*)(Wz + (long)(half*1024 + it*256 + tid)*8);
  };
  auto writePre = [&](){
    #pragma unroll
    for (int it=0; it<4; ++it)
      *(bf16x8*)&sW[(it*256+tid)*8] = pre[it];
  };
  auto zacc = [&](){
    #pragma unroll
    for (int mi=0;mi<2;++mi)
      #pragma unroll
      for (int ni=0;ni<8;++ni) acc[mi][ni]=(f32x4){0.f,0.f,0.f,0.f};
  };
  auto mfmaB = [&](int half){
    #pragma unroll
    for (int k2=0;k2<2;k2++){
      int kc = half*2 + k2;
      #pragma unroll
      for (int ni=0;ni<8;ni++){
        bf16x8 w = *(bf16x8*)&sW[(k2*512 + ni*64 + lane)*8];
        acc[0][ni]=mfma16(w,fb[0][kc],acc[0][ni]);
        acc[1][ni]=mfma16(w,fb[1][kc],acc[1][ni]);
      }
    }
  };
  auto mfmaH = [&](int half){
    #pragma unroll
    for (int k2=0;k2<2;k2++){
      int kc = half*2 + k2;
      bf16x8 h0=*(bf16x8*)&sH[(rloc0   )*LDT + kc*32 + quad*8];
      bf16x8 h1=*(bf16x8*)&sH[(rloc0+16)*LDT + kc*32 + quad*8];
      #pragma unroll
      for (int ni=0;ni<8;ni++){
        bf16x8 w = *(bf16x8*)&sW[(k2*512 + ni*64 + lane)*8];
        acc[0][ni]=mfma16(w,h0,acc[0][ni]);
        acc[1][ni]=mfma16(w,h1,acc[1][ni]);
      }
    }
  };
  auto fEpi = [&](){
    float fb2v = Fb2[0];
    #pragma unroll
    for (int mi=0;mi<2;++mi){
      float p = 0.f;
      #pragma unroll
      for (int ni=0;ni<8;++ni){
        int n0 = ni*16 + quad*4;
        float4 bb = *(const float4*)(Fb1 + n0);
        float4 w2 = *(const float4*)(FW2v + n0);
        p += silu_f(acc[mi][ni][0]+bb.x)*w2.x;
        p += silu_f(acc[mi][ni][1]+bb.y)*w2.y;
        p += silu_f(acc[mi][ni][2]+bb.z)*w2.z;
        p += silu_f(acc[mi][ni][3]+bb.w)*w2.w;
      }
      p += __shfl_xor(p,16);
      p += __shfl_xor(p,32);
      eF[mi] = p + fb2v;
    }
  };
  auto hEpi = [&](const float* __restrict__ b1){
    #pragma unroll
    for (int mi=0;mi<2;++mi){
      int rl = wv*32 + mi*16 + l15;
      #pragma unroll
      for (int ni=0;ni<8;++ni){
        int n0 = ni*16 + quad*4;
        float4 bb = *(const float4*)(b1 + n0);
        bf16x4 h;
        h[0]=(__bf16)silu_f(acc[mi][ni][0]+bb.x);
        h[1]=(__bf16)silu_f(acc[mi][ni][1]+bb.y);
        h[2]=(__bf16)silu_f(acc[mi][ni][2]+bb.z);
        h[3]=(__bf16)silu_f(acc[mi][ni][3]+bb.w);
        *(bf16x4*)&sH[rl*LDT + n0] = h;
      }
    }
  };
  // MLP output (x bias x mul) -> sH (wave-private rows), bf16
  auto outLDS = [&](const float* __restrict__ b2, const float* mul){
    #pragma unroll
    for (int mi=0;mi<2;++mi){
      int rl = wv*32 + mi*16 + l15;
      #pragma unroll
      for (int ni=0;ni<8;++ni){
        int n0 = ni*16 + quad*4;
        float4 bb = *(const float4*)(b2 + n0);
        bf16x4 o;
        o[0]=(__bf16)((acc[mi][ni][0]+bb.x)*mul[mi]);
        o[1]=(__bf16)((acc[mi][ni][1]+bb.y)*mul[mi]);
        o[2]=(__bf16)((acc[mi][ni][2]+bb.z)*mul[mi]);
        o[3]=(__bf16)((acc[mi][ni][3]+bb.w)*mul[mi]);
        *(bf16x4*)&sH[rl*LDT + n0] = o;
      }
    }
  };
  // wave wv reduces edges [32wv,32wv+32) over all 128 cols: fi += val*dir
  auto reduceFi = [&](){
    const int d = lane*2;
    float a0=0.f,a1=0.f,a2=0.f,a3=0.f,a4=0.f,a5=0.f;
    int cur = sE[wv*32];
    for (int i=0;i<32;i++){
      int e = wv*32+i;
      int n = sE[e];
      if (n != cur){                    // wave-uniform
        atomicAdd(&fiG[(long)cur*384 + d*3+0], a0);
        atomicAdd(&fiG[(long)cur*384 + d*3+1], a1);
        atomicAdd(&fiG[(long)cur*384 + d*3+2], a2);
        atomicAdd(&fiG[(long)cur*384 + (d+1)*3+0], a3);
        atomicAdd(&fiG[(long)cur*384 + (d+1)*3+1], a4);
        atomicAdd(&fiG[(long)cur*384 + (d+1)*3+2], a5);
        a0=a1=a2=a3=a4=a5=0.f; cur=n;
      }
      bf16x2 v = *(bf16x2*)&sH[e*LDT + d];
      float vx=(float)v[0], vy=(float)v[1];
      float d0=sDir[e*3+0], d1=sDir[e*3+1], d2=sDir[e*3+2];
      a0+=vx*d0; a1+=vx*d1; a2+=vx*d2;
      a3+=vy*d0; a4+=vy*d1; a5+=vy*d2;
    }
    atomicAdd(&fiG[(long)cur*384 + d*3+0], a0);
    atomicAdd(&fiG[(long)cur*384 + d*3+1], a1);
    atomicAdd(&fiG[(long)cur*384 + d*3+2], a2);
    atomicAdd(&fiG[(long)cur*384 + (d+1)*3+0], a3);
    atomicAdd(&fiG[(long)cur*384 + (d+1)*3+1], a4);
    atomicAdd(&fiG[(long)cur*384 + (d+1)*3+2], a5);
  };
  auto reducePhi = [&](){
    const int d = lane*2;
    float a0=0.f,a1=0.f;
    int cur = sE[wv*32];
    for (int i=0;i<32;i++){
      int e = wv*32+i;
      int n = sE[e];
      if (n != cur){
        atomicAdd(&phiG[(long)cur*DIM + d  ], a0);
        atomicAdd(&phiG[(long)cur*DIM + d+1], a1);
        a0=a1=0.f; cur=n;
      }
      bf16x2 v = *(bf16x2*)&sH[e*LDT + d];
      a0 += (float)v[0]; a1 += (float)v[1];
    }
    atomicAdd(&phiG[(long)cur*DIM + d  ], a0);
    atomicAdd(&phiG[(long)cur*DIM + d+1], a1);
  };

  // ---------------- pipeline ----------------
  preload(FW1z,0);
  __syncthreads(); writePre(); __syncthreads(); preload(FW1z,1);
  zacc(); mfmaB(0);
  __syncthreads(); writePre(); __syncthreads(); preload(fW1z,0);
  mfmaB(1);
  __syncthreads(); writePre(); __syncthreads(); preload(fW1z,1);
  fEpi();
  zacc(); mfmaB(0);
  __syncthreads(); writePre(); __syncthreads(); preload(fW2z,0);
  mfmaB(1);
  __syncthreads(); writePre(); __syncthreads(); preload(fW2z,1);
  hEpi(fb1);
  zacc(); mfmaH(0);
  __syncthreads(); writePre(); __syncthreads();
  if constexpr (WITH_R) preload(rW1z,0);
  mfmaH(1);
  outLDS(fb2, eF);                 // ef -> sH (own rows)
  __syncthreads();                 // ef visible to all; sW reads drained
  if constexpr (WITH_R) writePre();
  reduceFi();                      // fi += ef*dir (atomics)
  __syncthreads();                 // reduction reads done; sW publish

  if constexpr (WITH_R){
    preload(rW1z,1);
    zacc(); mfmaB(0);
    __syncthreads(); writePre(); __syncthreads(); preload(rW2z,0);
    mfmaB(1);
    __syncthreads(); writePre(); __syncthreads(); preload(rW2z,1);
    hEpi(rb1);
    zacc(); mfmaH(0);
    __syncthreads(); writePre(); __syncthreads();
    mfmaH(1);
    outLDS(rb2, swr);              // ephi -> sH (own rows)
    __syncthreads();
    reducePhi();                   // phi += ephi (atomics)
  }
}

// ===========================================================================
// Node MLP a: 1-wave blocks, 16 rows each -> 625 blocks. Exact fit.
// ===========================================================================
__global__ __launch_bounds__(64,4) void mlp_a(
    const float* __restrict__ X,
    const __bf16* __restrict__ W1z, const float* __restrict__ b1,
    const __bf16* __restrict__ W2z, const float* __restrict__ b2,
    __bf16* __restrict__ Y)
{
  __shared__ __bf16 sH[16*LDT];
  const int lane=threadIdx.x, l15=lane&15, quad=lane>>4;
  const long row0=(long)blockIdx.x*16;
  const long rA=row0+l15;

  bf16x8 fa[4];
  #pragma unroll
  for (int kc=0;kc<4;kc++){
    int kb=kc*32+quad*8;
    float4 u0 = *(const float4*)(X + rA*DIM + kb);
    float4 u1 = *(const float4*)(X + rA*DIM + kb + 4);
    bf16x8 a;
    a[0]=(__bf16)u0.x;a[1]=(__bf16)u0.y;a[2]=(__bf16)u0.z;a[3]=(__bf16)u0.w;
    a[4]=(__bf16)u1.x;a[5]=(__bf16)u1.y;a[6]=(__bf16)u1.z;a[7]=(__bf16)u1.w;
    fa[kc]=a;
  }

  f32x4 acc[8];
  #pragma unroll
  for (int ni=0;ni<8;++ni) acc[ni]=(f32x4){0.f,0.f,0.f,0.f};
  #pragma unroll
  for (int kc=0;kc<4;kc++){
    #pragma unroll
    for (int ni=0;ni<8;ni++){
      bf16x8 w = *(const bf16x8*)(W1z + (long)(kc*512 + ni*64 + lane)*8);
      acc[ni]=mfma16(w,fa[kc],acc[ni]);
    }
  }
  #pragma unroll
  for (int ni=0;ni<8;++ni){
    int n0 = ni*16 + quad*4;
    float4 bb = *(const float4*)(b1 + n0);
    bf16x4 h;
    h[0]=(__bf16)silu_f(acc[ni][0]+bb.x);
    h[1]=(__bf16)silu_f(acc[ni][1]+bb.y);
    h[2]=(__bf16)silu_f(acc[ni][2]+bb.z);
    h[3]=(__bf16)silu_f(acc[ni][3]+bb.w);
    *(bf16x4*)&sH[l15*LDT + n0] = h;
  }
  #pragma unroll
  for (int ni=0;ni<8;++ni) acc[ni]=(f32x4){0.f,0.f,0.f,0.f};
  #pragma unroll
  for (int kc=0;kc<4;kc++){
    bf16x8 h0=*(bf16x8*)&sH[l15*LDT + kc*32 + quad*8];
    #pragma unroll
    for (int ni=0;ni<8;ni++){
      bf16x8 w = *(const bf16x8*)(W2z + (long)(kc*512 + ni*64 + lane)*8);
      acc[ni]=mfma16(w,h0,acc[ni]);
    }
  }
  #pragma unroll
  for (int ni=0;ni<8;++ni){
    int n0 = ni*16 + quad*4;
    float4 bb = *(const float4*)(b2 + n0);
    bf16x4 o;
    o[0]=(__bf16)(acc[ni][0]+bb.x);
    o[1]=(__bf16)(acc[ni][1]+bb.y);
    o[2]=(__bf16)(acc[ni][2]+bb.z);
    o[3]=(__bf16)(acc[ni][3]+bb.w);
    *(bf16x4*)(Y + rA*DIM + n0) = o;
  }
}

// ===========================================================================
// One-shot setup: weight swizzle + seg offsets + node init + edge geometry
// ===========================================================================
__global__ __launch_bounds__(256) void setup_all(
    WPtrs wp, __bf16* __restrict__ wt,
    const int* __restrict__ esrc, int* __restrict__ row_start,
    const int* __restrict__ species, const float* __restrict__ spW,
    const float* __restrict__ spB, float* __restrict__ xi, float* __restrict__ fi,
    float* __restrict__ phi,
    const float* __restrict__ dist, const float* __restrict__ vec,
    const float* __restrict__ swv, float* __restrict__ dir, float* __restrict__ rb)
{
  const int b = blockIdx.x, tid = threadIdx.x;
  if (b < 33){
    int t = b/3, l = b%3;
    const float* src = wp.p[t] + (size_t)l*16384;
    __bf16* out = wt + (size_t)b*16384;
    for (int it=0; it<8; ++it){
      int fi_ = it*256 + tid;
      int kc = fi_>>9, ni = (fi_>>6)&7, lane = fi_&63;
      int n  = ni*16 + (lane&15);
      int k0 = kc*32 + (lane>>4)*8;
      bf16x8 v;
      #pragma unroll
      for (int j=0;j<8;++j) v[j] = (__bf16)src[(k0+j)*DIM + n];
      *(bf16x8*)(out + (size_t)fi_*8) = v;
    }
  } else if (b < 73){
    int t = (b-33)*256 + tid;
    if (t <= N_NODES){
      int lo = 0, hi = N_EDGES;
      while (lo < hi){ int mid = (lo+hi)>>1; if (esrc[mid] < t) lo = mid+1; else hi = mid; }
      row_start[t] = lo;
    }
  } else if (b < 73 + 5000){
    int idx = (b-73)*256 + tid;     // < N*128
    int n = idx >> 7, d = idx & 127;
    xi[idx] = spW[species[n]*DIM + d] + spB[d];
    phi[idx] = 0.f;
    fi[n*384 + d*3 + 0] = 0.f;
    fi[n*384 + d*3 + 1] = 0.f;
    fi[n*384 + d*3 + 2] = 0.f;
  } else {
    int e = (b-5073)*256 + tid;
    if (e < N_EDGES){
      float d = dist[e];
      float s = swv[e];
      float inv = s / d;
      dir[e*3+0] = vec[e*3+0]*inv;
      dir[e*3+1] = vec[e*3+1]*inv;
      dir[e*3+2] = vec[e*3+2]*inv;
      const float eta = (16.0f/5.0f)*(16.0f/5.0f);
      #pragma unroll
      for (int j=0;j<NBASIS;j++){
        float c = (float)j * (5.0f/15.0f);
        float t2 = d - c;
        rb[e*NBASIS + j] = __expf(-eta*t2*t2);
      }
    }
  }
}

// mij = ai[src]*ai[dst]*(rb@radW + radB)*sw  AND  xi += segsum(mij).
// 64 edges/block, wave wv owns edges [16wv,16wv+16). radW cols in regs.
__global__ __launch_bounds__(256) void mij_segsum(
    const __bf16* __restrict__ ai, const int* __restrict__ esrc, const int* __restrict__ edst,
    const float* __restrict__ swv, const float* __restrict__ rb,
    const float* __restrict__ radW, const float* __restrict__ radB,
    __bf16* __restrict__ mij, float* __restrict__ xi)
{
  __shared__ float sRb[64*NBASIS];
  __shared__ int   sS[64], sD[64];
  __shared__ float sSw[64];
  int tid = threadIdx.x;
  int e0 = blockIdx.x * 64;
  *(float4*)(sRb + tid*4) = *(const float4*)(rb + (long)e0*NBASIS + tid*4);
  if (tid < 64){
    sS[tid]  = esrc[e0+tid];
    sD[tid]  = edst[e0+tid];
    sSw[tid] = swv[e0+tid];
  }
  const int wv = tid>>6, lane = tid&63;
  const int d = lane*2;
  float2 rw[NBASIS];
  #pragma unroll
  for (int j=0;j<NBASIS;j++)
    rw[j] = *(const float2*)(radW + j*DIM + d);
  float2 rB = *(const float2*)(radB + d);
  __syncthreads();

  float sx=0.f, sy=0.f;
  int cur = sS[wv*16];
  #pragma unroll
  for (int i=0;i<16;i++){
    int el = wv*16 + i;
    int n = sS[el];
    if (n != cur){                       // wave-uniform branch
      atomicAdd(&xi[(long)cur*DIM+d  ], sx);
      atomicAdd(&xi[(long)cur*DIM+d+1], sy);
      sx=0.f; sy=0.f; cur=n;
    }
    bf16x2 as = *(const bf16x2*)(ai + (long)n*DIM + d);
    bf16x2 ad = *(const bf16x2*)(ai + (long)sD[el]*DIM + d);
    float acc0 = 0.f, acc1 = 0.f;
    #pragma unroll
    for (int j=0;j<NBASIS;j++){
      float rbv = sRb[el*NBASIS+j];
      acc0 += rbv*rw[j].x;
      acc1 += rbv*rw[j].y;
    }
    float sw_ = sSw[el];
    float m0 = (float)as[0]*(float)ad[0]*(acc0+rB.x)*sw_;
    float m1 = (float)as[1]*(float)ad[1]*(acc1+rB.y)*sw_;
    bf16x2 m; m[0]=(__bf16)m0; m[1]=(__bf16)m1;
    *(bf16x2*)(mij + (long)(e0+el)*DIM + d) = m;
    sx += m0; sy += m1;
  }
  atomicAdd(&xi[(long)cur*DIM+d  ], sx);
  atomicAdd(&xi[(long)cur*DIM+d+1], sy);
}

// r16: elementwise node update -- fi/phi already fully accumulated by
// mlp_layer's in-kernel reductions. di, scal, xi update; zero phi for next
// layer; write d_out on last layer.
__global__ __launch_bounds__(256) void node_update(
    const float* __restrict__ Rv, const float* __restrict__ uv,
    float* __restrict__ fi, float* __restrict__ di, float* __restrict__ xi,
    float* __restrict__ phi, float* __restrict__ out, int layer)
{
  int idx = blockIdx.x*256 + threadIdx.x;   // < N*128
  int n = idx >> 7;
  int d = idx & 127;
  float f0 = fi[n*384+d*3+0];
  float f1 = fi[n*384+d*3+1];
  float f2 = fi[n*384+d*3+2];
  float phi_v = (layer > 0) ? phi[idx] : 0.f;
  float Rv_ = Rv[idx];
  float sc = 0.f;
  float fv[3] = {f0,f1,f2};
  #pragma unroll
  for (int k=0;k<3;k++){
    float delta = Rv_*fv[k];
    float dv = (layer==0) ? delta : phi_v*di[n*384+d*3+k] + delta;
    di[n*384+d*3+k] = dv;
    sc += fv[k]*dv;
  }
  float nx = xi[idx] - uv[idx]*sc;
  xi[idx] = nx;
  phi[idx] = 0.f;                 // ready for next layer's accumulation
  if (layer == 2) out[idx] = nx;
}

extern "C" void kernel_launch(void* const* d_in, const int* in_sizes, int n_in,
                              void* d_out, int out_size, void* d_ws, size_t ws_size,
                              hipStream_t stream) {
  const int*   species = (const int*)  d_in[0];
  const int*   esrc    = (const int*)  d_in[1];
  const int*   edst    = (const int*)  d_in[2];
  const float* dist    = (const float*)d_in[3];
  const float* vec     = (const float*)d_in[4];
  const float* swv     = (const float*)d_in[5];
  const float* spW     = (const float*)d_in[6];
  const float* spB     = (const float*)d_in[7];
  const float* radW    = (const float*)d_in[8];
  const float* radB    = (const float*)d_in[9];
  const float* aW1=(const float*)d_in[10], *aB1=(const float*)d_in[11], *aW2=(const float*)d_in[12], *aB2=(const float*)d_in[13];
  const float* FW1=(const float*)d_in[14], *FB1=(const float*)d_in[15], *FW2=(const float*)d_in[16], *FB2=(const float*)d_in[17];
  const float* fW1=(const float*)d_in[18], *fB1=(const float*)d_in[19], *fW2=(const float*)d_in[20], *fB2=(const float*)d_in[21];
  const float* RW1=(const float*)d_in[22], *RB1=(const float*)d_in[23], *RW2=(const float*)d_in[24], *RB2=(const float*)d_in[25];
  const float* rW1=(const float*)d_in[26], *rB1=(const float*)d_in[27], *rW2=(const float*)d_in[28], *rB2=(const float*)d_in[29];
  const float* uW1=(const float*)d_in[30], *uB1=(const float*)d_in[31], *uW2=(const float*)d_in[32], *uB2=(const float*)d_in[33];

  const long NF = (long)N_NODES*DIM;      // 1,280,000
  const long EF = (long)N_EDGES*DIM;      // 20,480,000
  float* ws   = (float*)d_ws;
  float* xi   = ws;
  float* Rv   = xi   + NF;
  float* uv   = Rv   + NF;
  float* phi  = uv   + NF;
  float* fi   = phi  + NF;
  float* di   = fi   + 3*NF;
  float* dir  = di   + 3*NF;
  float* rb   = dir  + 3L*N_EDGES;
  int* row_start = (int*)(rb + 16L*N_EDGES);
  char* bp = (char*)(row_start + N_NODES + 2);
  size_t off = ((size_t)(bp - (char*)d_ws) + 15) & ~(size_t)15;
  __bf16* ai   = (__bf16*)((char*)d_ws + off);
  __bf16* mij  = ai  + NF;
  __bf16* wt   = mij + EF;                // 33 x 128x128 bf16 (swizzled)

  // swizzled bf16 weights: tensor order a1,a2,F1,f1,f2,R1,R2,r1,r2,u1,u2
  WPtrs wp;
  wp.p[0]=aW1; wp.p[1]=aW2; wp.p[2]=FW1; wp.p[3]=fW1; wp.p[4]=fW2;
  wp.p[5]=RW1; wp.p[6]=RW2; wp.p[7]=rW1; wp.p[8]=rW2; wp.p[9]=uW1; wp.p[10]=uW2;

  // one-shot setup: 33 convert + 40 seg + 5000 init + 625 geom = 5698 blocks
  setup_all<<<5698, 256, 0, stream>>>(wp, wt, esrc, row_start,
                                      species, spW, spB, xi, fi, phi,
                                      dist, vec, swv, dir, rb);

  const int nodeB = (N_NODES + 63)/64;        // 157 (node part of mlp_layer)
  const int edgeB = N_EDGES/128;              // 1250
  #define WT(t,l) (wt + (size_t)((t)*3+(l))*16384)

  for (int l=0;l<3;l++){
    const long bo = (long)l*DIM;

    // ai = mlp_a(xi)
    mlp_a<<<N_NODES/16, 64, 0, stream>>>(xi, WT(0,l), aB1+bo, WT(1,l), aB2+bo, ai);
    // mij (bf16) + xi += segsum(mij)   [fused, atomics]
    mij_segsum<<<N_EDGES/64, 256, 0, stream>>>(ai, esrc, edst, swv, rb,
                                               radW + (long)l*NBASIS*DIM, radB + bo,
                                               mij, xi);
    // combined: [node] Rv,uv  +  [edge] f/F[/r] MLPs with in-kernel
    // fi/phi segment reductions (no ef/ephi in HBM)
    if (l == 0)
      mlp_layer<false><<<nodeB+edgeB, 256, 0, stream>>>(
          nodeB, mij, esrc, dir,
          WT(3,l), fB1+bo, WT(4,l), fB2+bo,
          WT(2,l), FB1+bo, FW2+(long)l*DIM, FB2+l,
          nullptr, nullptr, nullptr, nullptr, nullptr,
          fi, phi,
          xi, WT(5,l), RB1+bo, WT(6,l), RB2+bo,
          WT(9,l), uB1+bo, WT(10,l), uB2+bo, Rv, uv);
    else
      mlp_layer<true><<<nodeB+edgeB, 256, 0, stream>>>(
          nodeB, mij, esrc, dir,
          WT(3,l), fB1+bo, WT(4,l), fB2+bo,
          WT(2,l), FB1+bo, FW2+(long)l*DIM, FB2+l,
          WT(7,l), rB1+bo, WT(8,l), rB2+bo, swv,
          fi, phi,
          xi, WT(5,l), RB1+bo, WT(6,l), RB2+bo,
          WT(9,l), uB1+bo, WT(10,l), uB2+bo, Rv, uv);
    // di, scal, xi (+ d_out on last layer); zeroes phi for next layer
    node_update<<<5000, 256, 0, stream>>>(Rv, uv, fi, di, xi, phi,
                                          (float*)d_out, l);
  }
}

// Round 17
// 512.101 us; speedup vs baseline: 1.3960x; 1.3960x over previous
//
#include <hip/hip_runtime.h>
#include <hip/hip_bf16.h>

#define N_NODES 10000
#define N_EDGES 160000
#define DIM     128
#define NBASIS  16
#define LDT     136   // LDS row stride (bf16); 272B row, 16B aligned
#define NFE     (N_NODES*DIM)   // 1,280,000 elements per plane

typedef __bf16 bf16x8 __attribute__((ext_vector_type(8)));
typedef __bf16 bf16x4 __attribute__((ext_vector_type(4)));
typedef __bf16 bf16x2 __attribute__((ext_vector_type(2)));
typedef float  f32x4  __attribute__((ext_vector_type(4)));

__device__ __forceinline__ float silu_f(float x){
  return x * (1.0f / (1.0f + __expf(-x)));
}
__device__ __forceinline__ f32x4 mfma16(bf16x8 a, bf16x8 b, f32x4 c){
  return __builtin_amdgcn_mfma_f32_16x16x32_bf16(a,b,c,0,0,0);
}

// Swizzled weight layout: frag (kc,ni,lane) at Wz[(kc*512+ni*64+lane)*8+j].
// Design log: r9 LDS weights 140->90; r10 operand-swap 90->81; r11 fused
// mij+segsum 728->663; r12 reg radW 663->622; r13 node-MLP merge 622->550;
// r15 barrier reorder 545 (best); r16 in-kernel fi/phi reduction REGRESSED
// 715: fi atomics at 24B stride ([n][d][3] layout) -> 64B-sector write
// amplification (+70MB) + L2 RMW serialization. r17 FIX: fi/di stored as
// 3 planes [k][n][d] -> every atomic burst is wave-contiguous 512B (the
// proven xi-segsum pattern). ef/ephi still never touch HBM.
// r8 lesson: smaller edge tiles double chip-wide weight traffic.
// r6 lesson: never force min-waves that cap VGPR below live state.

struct WPtrs { const float* p[11]; };

// ===========================================================================
// Combined per-layer MLP dispatch.
//  blocks [0, nodeB):   R- and u-MLPs on xi (64 rows/block, 4 indep waves)
//  blocks [nodeB, ...): edge MLPs on mij (128 edges/block) + in-kernel
//                       segment reduction of ef*dir -> fi planes, ephi -> phi.
// ===========================================================================
template<bool WITH_R>
__global__ __launch_bounds__(256,3) void mlp_layer(
    int nodeB,
    const __bf16* __restrict__ mij,
    const int*    __restrict__ esrc, const float* __restrict__ dirv,
    const __bf16* __restrict__ fW1z, const float* __restrict__ fb1,
    const __bf16* __restrict__ fW2z, const float* __restrict__ fb2,
    const __bf16* __restrict__ FW1z, const float* __restrict__ Fb1,
    const float*  __restrict__ FW2v, const float* __restrict__ Fb2,
    const __bf16* __restrict__ rW1z, const float* __restrict__ rb1,
    const __bf16* __restrict__ rW2z, const float* __restrict__ rb2,
    const float*  __restrict__ swv,
    float* __restrict__ fiG, float* __restrict__ phiG,
    const float* __restrict__ X,
    const __bf16* __restrict__ RW1z, const float* __restrict__ Rb1,
    const __bf16* __restrict__ RW2z, const float* __restrict__ Rb2,
    const __bf16* __restrict__ uW1z, const float* __restrict__ ub1,
    const __bf16* __restrict__ uW2z, const float* __restrict__ ub2,
    float* __restrict__ Rv, float* __restrict__ uv)
{
  __shared__ __bf16 sH[128*LDT];   // 34816 B
  __shared__ __bf16 sW[8192];      // 16384 B
  __shared__ int    sE[128];       //   512 B
  __shared__ float  sDir[128*3];   //  1536 B   (total 53248 -> 3 blocks/CU)
  const int tid=threadIdx.x, lane=tid&63, wv=tid>>6, l15=lane&15, quad=lane>>4;

  if ((int)blockIdx.x < nodeB){
    // ---------------- node path: R and u MLPs, 16 rows per wave -----------
    const long row0n = (long)blockIdx.x*64 + wv*16;
    const long rA = row0n + l15;
    const bool okA = rA < N_NODES;

    bf16x8 fa[4];
    #pragma unroll
    for (int kc=0;kc<4;kc++){
      int kb=kc*32+quad*8;
      bf16x8 a;
      #pragma unroll
      for (int i=0;i<8;i++) a[i]=(__bf16)0.f;
      if (okA){
        float4 u0 = *(const float4*)(X + rA*DIM + kb);
        float4 u1 = *(const float4*)(X + rA*DIM + kb + 4);
        a[0]=(__bf16)u0.x;a[1]=(__bf16)u0.y;a[2]=(__bf16)u0.z;a[3]=(__bf16)u0.w;
        a[4]=(__bf16)u1.x;a[5]=(__bf16)u1.y;a[6]=(__bf16)u1.z;a[7]=(__bf16)u1.w;
      }
      fa[kc]=a;
    }

    f32x4 acc[8];
    auto zacc = [&](){
      #pragma unroll
      for (int ni=0;ni<8;++ni) acc[ni]=(f32x4){0.f,0.f,0.f,0.f};
    };
    auto gemmA = [&](const __bf16* __restrict__ Wz){
      #pragma unroll
      for (int kc=0;kc<4;kc++){
        #pragma unroll
        for (int ni=0;ni<8;ni++){
          bf16x8 w = *(const bf16x8*)(Wz + (long)(kc*512 + ni*64 + lane)*8);
          acc[ni]=mfma16(w,fa[kc],acc[ni]);
        }
      }
    };
    auto gemmH = [&](const __bf16* __restrict__ Wz){
      #pragma unroll
      for (int kc=0;kc<4;kc++){
        bf16x8 h0=*(bf16x8*)&sH[(wv*16+l15)*LDT + kc*32 + quad*8];
        #pragma unroll
        for (int ni=0;ni<8;ni++){
          bf16x8 w = *(const bf16x8*)(Wz + (long)(kc*512 + ni*64 + lane)*8);
          acc[ni]=mfma16(w,h0,acc[ni]);
        }
      }
    };
    auto hEpi = [&](const float* __restrict__ b1){
      #pragma unroll
      for (int ni=0;ni<8;++ni){
        int n0 = ni*16 + quad*4;
        float4 bb = *(const float4*)(b1 + n0);
        bf16x4 h;
        h[0]=(__bf16)silu_f(acc[ni][0]+bb.x);
        h[1]=(__bf16)silu_f(acc[ni][1]+bb.y);
        h[2]=(__bf16)silu_f(acc[ni][2]+bb.z);
        h[3]=(__bf16)silu_f(acc[ni][3]+bb.w);
        *(bf16x4*)&sH[(wv*16+l15)*LDT + n0] = h;
      }
    };
    auto cStoreF = [&](const float* __restrict__ b2, float* __restrict__ Y){
      if (okA){
        #pragma unroll
        for (int ni=0;ni<8;++ni){
          int n0 = ni*16 + quad*4;
          float4 bb = *(const float4*)(b2 + n0);
          float4 o;
          o.x=acc[ni][0]+bb.x; o.y=acc[ni][1]+bb.y;
          o.z=acc[ni][2]+bb.z; o.w=acc[ni][3]+bb.w;
          *(float4*)(Y + rA*DIM + n0) = o;
        }
      }
    };

    zacc(); gemmA(RW1z); hEpi(Rb1);
    zacc(); gemmH(RW2z); cStoreF(Rb2, Rv);
    zacc(); gemmA(uW1z); hEpi(ub1);
    zacc(); gemmH(uW2z); cStoreF(ub2, uv);
    return;
  }

  // ---------------- edge path: F/f[/r] MLPs on mij ------------------------
  const long row0 = (long)(blockIdx.x - nodeB)*128;
  const int  rloc0 = wv*32 + l15;
  const long rB0 = row0 + rloc0, rB1 = rB0+16;

  // stage esrc + dir for this block's 128 edges
  if (tid < 32)  *(int4*)&sE[tid*4]    = *(const int4*)(esrc + row0 + tid*4);
  if (tid >= 64 && tid < 160)
    *(float4*)&sDir[(tid-64)*4] = *(const float4*)(dirv + row0*3 + (tid-64)*4);

  bf16x8 fb[2][4];
  #pragma unroll
  for (int kc=0;kc<4;kc++){
    fb[0][kc] = *(const bf16x8*)(mij + rB0*DIM + kc*32 + quad*8);
    fb[1][kc] = *(const bf16x8*)(mij + rB1*DIM + kc*32 + quad*8);
  }
  float swr[2];
  if constexpr (WITH_R){ swr[0]=swv[rB0]; swr[1]=swv[rB1]; }

  f32x4 acc[2][8];
  bf16x8 pre[4];
  float eF[2];

  auto preload = [&](const __bf16* __restrict__ Wz, int half){
    #pragma unroll
    for (int it=0; it<4; ++it)
      pre[it] = *(const bf16x8*)(Wz + (long)(half*1024 + it*256 + tid)*8);
  };
  auto writePre = [&](){
    #pragma unroll
    for (int it=0; it<4; ++it)
      *(bf16x8*)&sW[(it*256+tid)*8] = pre[it];
  };
  auto zacc = [&](){
    #pragma unroll
    for (int mi=0;mi<2;++mi)
      #pragma unroll
      for (int ni=0;ni<8;++ni) acc[mi][ni]=(f32x4){0.f,0.f,0.f,0.f};
  };
  auto mfmaB = [&](int half){
    #pragma unroll
    for (int k2=0;k2<2;k2++){
      int kc = half*2 + k2;
      #pragma unroll
      for (int ni=0;ni<8;ni++){
        bf16x8 w = *(bf16x8*)&sW[(k2*512 + ni*64 + lane)*8];
        acc[0][ni]=mfma16(w,fb[0][kc],acc[0][ni]);
        acc[1][ni]=mfma16(w,fb[1][kc],acc[1][ni]);
      }
    }
  };
  auto mfmaH = [&](int half){
    #pragma unroll
    for (int k2=0;k2<2;k2++){
      int kc = half*2 + k2;
      bf16x8 h0=*(bf16x8*)&sH[(rloc0   )*LDT + kc*32 + quad*8];
      bf16x8 h1=*(bf16x8*)&sH[(rloc0+16)*LDT + kc*32 + quad*8];
      #pragma unroll
      for (int ni=0;ni<8;ni++){
        bf16x8 w = *(bf16x8*)&sW[(k2*512 + ni*64 + lane)*8];
        acc[0][ni]=mfma16(w,h0,acc[0][ni]);
        acc[1][ni]=mfma16(w,h1,acc[1][ni]);
      }
    }
  };
  auto fEpi = [&](){
    float fb2v = Fb2[0];
    #pragma unroll
    for (int mi=0;mi<2;++mi){
      float p = 0.f;
      #pragma unroll
      for (int ni=0;ni<8;++ni){
        int n0 = ni*16 + quad*4;
        float4 bb = *(const float4*)(Fb1 + n0);
        float4 w2 = *(const float4*)(FW2v + n0);
        p += silu_f(acc[mi][ni][0]+bb.x)*w2.x;
        p += silu_f(acc[mi][ni][1]+bb.y)*w2.y;
        p += silu_f(acc[mi][ni][2]+bb.z)*w2.z;
        p += silu_f(acc[mi][ni][3]+bb.w)*w2.w;
      }
      p += __shfl_xor(p,16);
      p += __shfl_xor(p,32);
      eF[mi] = p + fb2v;
    }
  };
  auto hEpi = [&](const float* __restrict__ b1){
    #pragma unroll
    for (int mi=0;mi<2;++mi){
      int rl = wv*32 + mi*16 + l15;
      #pragma unroll
      for (int ni=0;ni<8;++ni){
        int n0 = ni*16 + quad*4;
        float4 bb = *(const float4*)(b1 + n0);
        bf16x4 h;
        h[0]=(__bf16)silu_f(acc[mi][ni][0]+bb.x);
        h[1]=(__bf16)silu_f(acc[mi][ni][1]+bb.y);
        h[2]=(__bf16)silu_f(acc[mi][ni][2]+bb.z);
        h[3]=(__bf16)silu_f(acc[mi][ni][3]+bb.w);
        *(bf16x4*)&sH[rl*LDT + n0] = h;
      }
    }
  };
  // MLP output (x bias x mul) -> sH (wave-private rows), bf16
  auto outLDS = [&](const float* __restrict__ b2, const float* mul){
    #pragma unroll
    for (int mi=0;mi<2;++mi){
      int rl = wv*32 + mi*16 + l15;
      #pragma unroll
      for (int ni=0;ni<8;++ni){
        int n0 = ni*16 + quad*4;
        float4 bb = *(const float4*)(b2 + n0);
        bf16x4 o;
        o[0]=(__bf16)((acc[mi][ni][0]+bb.x)*mul[mi]);
        o[1]=(__bf16)((acc[mi][ni][1]+bb.y)*mul[mi]);
        o[2]=(__bf16)((acc[mi][ni][2]+bb.z)*mul[mi]);
        o[3]=(__bf16)((acc[mi][ni][3]+bb.w)*mul[mi]);
        *(bf16x4*)&sH[rl*LDT + n0] = o;
      }
    }
  };
  // wave wv reduces edges [32wv,32wv+32) over all 128 cols: fi += val*dir.
  // r17: fi stored as 3 planes [k][n][128] -> atomics wave-contiguous.
  auto reduceFi = [&](){
    const int d = lane*2;
    float a0=0.f,a1=0.f,a2=0.f,a3=0.f,a4=0.f,a5=0.f;
    int cur = sE[wv*32];
    for (int i=0;i<32;i++){
      int e = wv*32+i;
      int n = sE[e];
      if (n != cur){                    // wave-uniform
        long b = (long)cur*DIM + d;
        atomicAdd(&fiG[0L*NFE + b  ], a0);
        atomicAdd(&fiG[0L*NFE + b+1], a3);
        atomicAdd(&fiG[1L*NFE + b  ], a1);
        atomicAdd(&fiG[1L*NFE + b+1], a4);
        atomicAdd(&fiG[2L*NFE + b  ], a2);
        atomicAdd(&fiG[2L*NFE + b+1], a5);
        a0=a1=a2=a3=a4=a5=0.f; cur=n;
      }
      bf16x2 v = *(bf16x2*)&sH[e*LDT + d];
      float vx=(float)v[0], vy=(float)v[1];
      float d0=sDir[e*3+0], d1=sDir[e*3+1], d2=sDir[e*3+2];
      a0+=vx*d0; a1+=vx*d1; a2+=vx*d2;
      a3+=vy*d0; a4+=vy*d1; a5+=vy*d2;
    }
    long b = (long)cur*DIM + d;
    atomicAdd(&fiG[0L*NFE + b  ], a0);
    atomicAdd(&fiG[0L*NFE + b+1], a3);
    atomicAdd(&fiG[1L*NFE + b  ], a1);
    atomicAdd(&fiG[1L*NFE + b+1], a4);
    atomicAdd(&fiG[2L*NFE + b  ], a2);
    atomicAdd(&fiG[2L*NFE + b+1], a5);
  };
  auto reducePhi = [&](){
    const int d = lane*2;
    float a0=0.f,a1=0.f;
    int cur = sE[wv*32];
    for (int i=0;i<32;i++){
      int e = wv*32+i;
      int n = sE[e];
      if (n != cur){
        atomicAdd(&phiG[(long)cur*DIM + d  ], a0);
        atomicAdd(&phiG[(long)cur*DIM + d+1], a1);
        a0=a1=0.f; cur=n;
      }
      bf16x2 v = *(bf16x2*)&sH[e*LDT + d];
      a0 += (float)v[0]; a1 += (float)v[1];
    }
    atomicAdd(&phiG[(long)cur*DIM + d  ], a0);
    atomicAdd(&phiG[(long)cur*DIM + d+1], a1);
  };

  // ---------------- pipeline ----------------
  preload(FW1z,0);
  __syncthreads(); writePre(); __syncthreads(); preload(FW1z,1);
  zacc(); mfmaB(0);
  __syncthreads(); writePre(); __syncthreads(); preload(fW1z,0);
  mfmaB(1);
  __syncthreads(); writePre(); __syncthreads(); preload(fW1z,1);
  fEpi();
  zacc(); mfmaB(0);
  __syncthreads(); writePre(); __syncthreads(); preload(fW2z,0);
  mfmaB(1);
  __syncthreads(); writePre(); __syncthreads(); preload(fW2z,1);
  hEpi(fb1);
  zacc(); mfmaH(0);
  __syncthreads(); writePre(); __syncthreads();
  if constexpr (WITH_R) preload(rW1z,0);
  mfmaH(1);
  outLDS(fb2, eF);                 // ef -> sH (own rows)
  __syncthreads();                 // ef visible to all
  if constexpr (WITH_R) writePre();
  reduceFi();                      // fi += ef*dir (plane atomics)
  __syncthreads();                 // reduction reads done; sW publish

  if constexpr (WITH_R){
    preload(rW1z,1);
    zacc(); mfmaB(0);
    __syncthreads(); writePre(); __syncthreads(); preload(rW2z,0);
    mfmaB(1);
    __syncthreads(); writePre(); __syncthreads(); preload(rW2z,1);
    hEpi(rb1);
    zacc(); mfmaH(0);
    __syncthreads(); writePre(); __syncthreads();
    mfmaH(1);
    outLDS(rb2, swr);              // ephi -> sH (own rows)
    __syncthreads();
    reducePhi();                   // phi += ephi (atomics)
  }
}

// ===========================================================================
// Node MLP a: 1-wave blocks, 16 rows each -> 625 blocks. Exact fit.
// ===========================================================================
__global__ __launch_bounds__(64,4) void mlp_a(
    const float* __restrict__ X,
    const __bf16* __restrict__ W1z, const float* __restrict__ b1,
    const __bf16* __restrict__ W2z, const float* __restrict__ b2,
    __bf16* __restrict__ Y)
{
  __shared__ __bf16 sH[16*LDT];
  const int lane=threadIdx.x, l15=lane&15, quad=lane>>4;
  const long row0=(long)blockIdx.x*16;
  const long rA=row0+l15;

  bf16x8 fa[4];
  #pragma unroll
  for (int kc=0;kc<4;kc++){
    int kb=kc*32+quad*8;
    float4 u0 = *(const float4*)(X + rA*DIM + kb);
    float4 u1 = *(const float4*)(X + rA*DIM + kb + 4);
    bf16x8 a;
    a[0]=(__bf16)u0.x;a[1]=(__bf16)u0.y;a[2]=(__bf16)u0.z;a[3]=(__bf16)u0.w;
    a[4]=(__bf16)u1.x;a[5]=(__bf16)u1.y;a[6]=(__bf16)u1.z;a[7]=(__bf16)u1.w;
    fa[kc]=a;
  }

  f32x4 acc[8];
  #pragma unroll
  for (int ni=0;ni<8;++ni) acc[ni]=(f32x4){0.f,0.f,0.f,0.f};
  #pragma unroll
  for (int kc=0;kc<4;kc++){
    #pragma unroll
    for (int ni=0;ni<8;ni++){
      bf16x8 w = *(const bf16x8*)(W1z + (long)(kc*512 + ni*64 + lane)*8);
      acc[ni]=mfma16(w,fa[kc],acc[ni]);
    }
  }
  #pragma unroll
  for (int ni=0;ni<8;++ni){
    int n0 = ni*16 + quad*4;
    float4 bb = *(const float4*)(b1 + n0);
    bf16x4 h;
    h[0]=(__bf16)silu_f(acc[ni][0]+bb.x);
    h[1]=(__bf16)silu_f(acc[ni][1]+bb.y);
    h[2]=(__bf16)silu_f(acc[ni][2]+bb.z);
    h[3]=(__bf16)silu_f(acc[ni][3]+bb.w);
    *(bf16x4*)&sH[l15*LDT + n0] = h;
  }
  #pragma unroll
  for (int ni=0;ni<8;++ni) acc[ni]=(f32x4){0.f,0.f,0.f,0.f};
  #pragma unroll
  for (int kc=0;kc<4;kc++){
    bf16x8 h0=*(bf16x8*)&sH[l15*LDT + kc*32 + quad*8];
    #pragma unroll
    for (int ni=0;ni<8;ni++){
      bf16x8 w = *(const bf16x8*)(W2z + (long)(kc*512 + ni*64 + lane)*8);
      acc[ni]=mfma16(w,h0,acc[ni]);
    }
  }
  #pragma unroll
  for (int ni=0;ni<8;++ni){
    int n0 = ni*16 + quad*4;
    float4 bb = *(const float4*)(b2 + n0);
    bf16x4 o;
    o[0]=(__bf16)(acc[ni][0]+bb.x);
    o[1]=(__bf16)(acc[ni][1]+bb.y);
    o[2]=(__bf16)(acc[ni][2]+bb.z);
    o[3]=(__bf16)(acc[ni][3]+bb.w);
    *(bf16x4*)(Y + rA*DIM + n0) = o;
  }
}

// ===========================================================================
// One-shot setup: weight swizzle + node init + edge geometry
// ===========================================================================
__global__ __launch_bounds__(256) void setup_all(
    WPtrs wp, __bf16* __restrict__ wt,
    const int* __restrict__ species, const float* __restrict__ spW,
    const float* __restrict__ spB, float* __restrict__ xi, float* __restrict__ fi,
    float* __restrict__ phi,
    const float* __restrict__ dist, const float* __restrict__ vec,
    const float* __restrict__ swv, float* __restrict__ dir, float* __restrict__ rb)
{
  const int b = blockIdx.x, tid = threadIdx.x;
  if (b < 33){
    int t = b/3, l = b%3;
    const float* src = wp.p[t] + (size_t)l*16384;
    __bf16* out = wt + (size_t)b*16384;
    for (int it=0; it<8; ++it){
      int fi_ = it*256 + tid;
      int kc = fi_>>9, ni = (fi_>>6)&7, lane = fi_&63;
      int n  = ni*16 + (lane&15);
      int k0 = kc*32 + (lane>>4)*8;
      bf16x8 v;
      #pragma unroll
      for (int j=0;j<8;++j) v[j] = (__bf16)src[(k0+j)*DIM + n];
      *(bf16x8*)(out + (size_t)fi_*8) = v;
    }
  } else if (b < 33 + 5000){
    int idx = (b-33)*256 + tid;     // < N*128
    int n = idx >> 7, d = idx & 127;
    xi[idx] = spW[species[n]*DIM + d] + spB[d];
    phi[idx] = 0.f;
    fi[idx] = 0.f;                  // plane 0
    fi[NFE + idx] = 0.f;            // plane 1
    fi[2L*NFE + idx] = 0.f;         // plane 2
  } else {
    int e = (b-5033)*256 + tid;
    if (e < N_EDGES){
      float d = dist[e];
      float s = swv[e];
      float inv = s / d;
      dir[e*3+0] = vec[e*3+0]*inv;
      dir[e*3+1] = vec[e*3+1]*inv;
      dir[e*3+2] = vec[e*3+2]*inv;
      const float eta = (16.0f/5.0f)*(16.0f/5.0f);
      #pragma unroll
      for (int j=0;j<NBASIS;j++){
        float c = (float)j * (5.0f/15.0f);
        float t2 = d - c;
        rb[e*NBASIS + j] = __expf(-eta*t2*t2);
      }
    }
  }
}

// mij = ai[src]*ai[dst]*(rb@radW + radB)*sw  AND  xi += segsum(mij).
// 64 edges/block, wave wv owns edges [16wv,16wv+16). radW cols in regs.
__global__ __launch_bounds__(256) void mij_segsum(
    const __bf16* __restrict__ ai, const int* __restrict__ esrc, const int* __restrict__ edst,
    const float* __restrict__ swv, const float* __restrict__ rb,
    const float* __restrict__ radW, const float* __restrict__ radB,
    __bf16* __restrict__ mij, float* __restrict__ xi)
{
  __shared__ float sRb[64*NBASIS];
  __shared__ int   sS[64], sD[64];
  __shared__ float sSw[64];
  int tid = threadIdx.x;
  int e0 = blockIdx.x * 64;
  *(float4*)(sRb + tid*4) = *(const float4*)(rb + (long)e0*NBASIS + tid*4);
  if (tid < 64){
    sS[tid]  = esrc[e0+tid];
    sD[tid]  = edst[e0+tid];
    sSw[tid] = swv[e0+tid];
  }
  const int wv = tid>>6, lane = tid&63;
  const int d = lane*2;
  float2 rw[NBASIS];
  #pragma unroll
  for (int j=0;j<NBASIS;j++)
    rw[j] = *(const float2*)(radW + j*DIM + d);
  float2 rB = *(const float2*)(radB + d);
  __syncthreads();

  float sx=0.f, sy=0.f;
  int cur = sS[wv*16];
  #pragma unroll
  for (int i=0;i<16;i++){
    int el = wv*16 + i;
    int n = sS[el];
    if (n != cur){                       // wave-uniform branch
      atomicAdd(&xi[(long)cur*DIM+d  ], sx);
      atomicAdd(&xi[(long)cur*DIM+d+1], sy);
      sx=0.f; sy=0.f; cur=n;
    }
    bf16x2 as = *(const bf16x2*)(ai + (long)n*DIM + d);
    bf16x2 ad = *(const bf16x2*)(ai + (long)sD[el]*DIM + d);
    float acc0 = 0.f, acc1 = 0.f;
    #pragma unroll
    for (int j=0;j<NBASIS;j++){
      float rbv = sRb[el*NBASIS+j];
      acc0 += rbv*rw[j].x;
      acc1 += rbv*rw[j].y;
    }
    float sw_ = sSw[el];
    float m0 = (float)as[0]*(float)ad[0]*(acc0+rB.x)*sw_;
    float m1 = (float)as[1]*(float)ad[1]*(acc1+rB.y)*sw_;
    bf16x2 m; m[0]=(__bf16)m0; m[1]=(__bf16)m1;
    *(bf16x2*)(mij + (long)(e0+el)*DIM + d) = m;
    sx += m0; sy += m1;
  }
  atomicAdd(&xi[(long)cur*DIM+d  ], sx);
  atomicAdd(&xi[(long)cur*DIM+d+1], sy);
}

// Elementwise node update: fi/phi fully accumulated by mlp_layer. Plane
// layout for fi/di. Zeroes phi + fi-increment... (fi persists across layers,
// only phi is per-layer). Writes d_out on last layer.
__global__ __launch_bounds__(256) void node_update(
    const float* __restrict__ Rv, const float* __restrict__ uv,
    float* __restrict__ fi, float* __restrict__ di, float* __restrict__ xi,
    float* __restrict__ phi, float* __restrict__ out, int layer)
{
  long idx = (long)blockIdx.x*256 + threadIdx.x;   // < N*128
  float f0 = fi[idx];
  float f1 = fi[NFE + idx];
  float f2 = fi[2L*NFE + idx];
  float phi_v = (layer > 0) ? phi[idx] : 0.f;
  float Rv_ = Rv[idx];
  float fv[3] = {f0,f1,f2};
  float sc = 0.f;
  #pragma unroll
  for (int k=0;k<3;k++){
    float delta = Rv_*fv[k];
    float dv = (layer==0) ? delta : phi_v*di[(long)k*NFE + idx] + delta;
    di[(long)k*NFE + idx] = dv;
    sc += fv[k]*dv;
  }
  float nx = xi[idx] - uv[idx]*sc;
  xi[idx] = nx;
  phi[idx] = 0.f;                 // ready for next layer's accumulation
  if (layer == 2) out[idx] = nx;
}

extern "C" void kernel_launch(void* const* d_in, const int* in_sizes, int n_in,
                              void* d_out, int out_size, void* d_ws, size_t ws_size,
                              hipStream_t stream) {
  const int*   species = (const int*)  d_in[0];
  const int*   esrc    = (const int*)  d_in[1];
  const int*   edst    = (const int*)  d_in[2];
  const float* dist    = (const float*)d_in[3];
  const float* vec     = (const float*)d_in[4];
  const float* swv     = (const float*)d_in[5];
  const float* spW     = (const float*)d_in[6];
  const float* spB     = (const float*)d_in[7];
  const float* radW    = (const float*)d_in[8];
  const float* radB    = (const float*)d_in[9];
  const float* aW1=(const float*)d_in[10], *aB1=(const float*)d_in[11], *aW2=(const float*)d_in[12], *aB2=(const float*)d_in[13];
  const float* FW1=(const float*)d_in[14], *FB1=(const float*)d_in[15], *FW2=(const float*)d_in[16], *FB2=(const float*)d_in[17];
  const float* fW1=(const float*)d_in[18], *fB1=(const float*)d_in[19], *fW2=(const float*)d_in[20], *fB2=(const float*)d_in[21];
  const float* RW1=(const float*)d_in[22], *RB1=(const float*)d_in[23], *RW2=(const float*)d_in[24], *RB2=(const float*)d_in[25];
  const float* rW1=(const float*)d_in[26], *rB1=(const float*)d_in[27], *rW2=(const float*)d_in[28], *rB2=(const float*)d_in[29];
  const float* uW1=(const float*)d_in[30], *uB1=(const float*)d_in[31], *uW2=(const float*)d_in[32], *uB2=(const float*)d_in[33];

  const long NF = (long)N_NODES*DIM;      // 1,280,000
  const long EF = (long)N_EDGES*DIM;      // 20,480,000
  float* ws   = (float*)d_ws;
  float* xi   = ws;
  float* Rv   = xi   + NF;
  float* uv   = Rv   + NF;
  float* phi  = uv   + NF;
  float* fi   = phi  + NF;                // 3 planes of NF
  float* di   = fi   + 3*NF;              // 3 planes of NF
  float* dir  = di   + 3*NF;
  float* rb   = dir  + 3L*N_EDGES;
  char* bp = (char*)(rb + 16L*N_EDGES);
  size_t off = ((size_t)(bp - (char*)d_ws) + 15) & ~(size_t)15;
  __bf16* ai   = (__bf16*)((char*)d_ws + off);
  __bf16* mij  = ai  + NF;
  __bf16* wt   = mij + EF;                // 33 x 128x128 bf16 (swizzled)

  // swizzled bf16 weights: tensor order a1,a2,F1,f1,f2,R1,R2,r1,r2,u1,u2
  WPtrs wp;
  wp.p[0]=aW1; wp.p[1]=aW2; wp.p[2]=FW1; wp.p[3]=fW1; wp.p[4]=fW2;
  wp.p[5]=RW1; wp.p[6]=RW2; wp.p[7]=rW1; wp.p[8]=rW2; wp.p[9]=uW1; wp.p[10]=uW2;

  // one-shot setup: 33 convert + 5000 init + 625 geom = 5658 blocks
  setup_all<<<5658, 256, 0, stream>>>(wp, wt,
                                      species, spW, spB, xi, fi, phi,
                                      dist, vec, swv, dir, rb);

  const int nodeB = (N_NODES + 63)/64;        // 157 (node part of mlp_layer)
  const int edgeB = N_EDGES/128;              // 1250
  #define WT(t,l) (wt + (size_t)((t)*3+(l))*16384)

  for (int l=0;l<3;l++){
    const long bo = (long)l*DIM;

    // ai = mlp_a(xi)
    mlp_a<<<N_NODES/16, 64, 0, stream>>>(xi, WT(0,l), aB1+bo, WT(1,l), aB2+bo, ai);
    // mij (bf16) + xi += segsum(mij)   [fused, atomics]
    mij_segsum<<<N_EDGES/64, 256, 0, stream>>>(ai, esrc, edst, swv, rb,
                                               radW + (long)l*NBASIS*DIM, radB + bo,
                                               mij, xi);
    // combined: [node] Rv,uv  +  [edge] f/F[/r] MLPs with in-kernel
    // fi/phi segment reductions (no ef/ephi in HBM; plane-coalesced atomics)
    if (l == 0)
      mlp_layer<false><<<nodeB+edgeB, 256, 0, stream>>>(
          nodeB, mij, esrc, dir,
          WT(3,l), fB1+bo, WT(4,l), fB2+bo,
          WT(2,l), FB1+bo, FW2+(long)l*DIM, FB2+l,
          nullptr, nullptr, nullptr, nullptr, nullptr,
          fi, phi,
          xi, WT(5,l), RB1+bo, WT(6,l), RB2+bo,
          WT(9,l), uB1+bo, WT(10,l), uB2+bo, Rv, uv);
    else
      mlp_layer<true><<<nodeB+edgeB, 256, 0, stream>>>(
          nodeB, mij, esrc, dir,
          WT(3,l), fB1+bo, WT(4,l), fB2+bo,
          WT(2,l), FB1+bo, FW2+(long)l*DIM, FB2+l,
          WT(7,l), rB1+bo, WT(8,l), rB2+bo, swv,
          fi, phi,
          xi, WT(5,l), RB1+bo, WT(6,l), RB2+bo,
          WT(9,l), uB1+bo, WT(10,l), uB2+bo, Rv, uv);
    // di, scal, xi (+ d_out on last layer); zeroes phi for next layer
    node_update<<<5000, 256, 0, stream>>>(Rv, uv, fi, di, xi, phi,
                                          (float*)d_out, l);
  }
}

// Round 18
// 504.674 us; speedup vs baseline: 1.4166x; 1.0147x over previous
//
#include <hip/hip_runtime.h>
#include <hip/hip_bf16.h>

#define N_NODES 10000
#define N_EDGES 160000
#define DIM     128
#define NBASIS  16
#define LDT     136   // LDS row stride (bf16); 272B row, 16B aligned
#define NFE     (N_NODES*DIM)   // 1,280,000 elements per plane

typedef __bf16 bf16x8 __attribute__((ext_vector_type(8)));
typedef __bf16 bf16x4 __attribute__((ext_vector_type(4)));
typedef __bf16 bf16x2 __attribute__((ext_vector_type(2)));
typedef float  f32x4  __attribute__((ext_vector_type(4)));

__device__ __forceinline__ float silu_f(float x){
  return x * (1.0f / (1.0f + __expf(-x)));
}
__device__ __forceinline__ f32x4 mfma16(bf16x8 a, bf16x8 b, f32x4 c){
  return __builtin_amdgcn_mfma_f32_16x16x32_bf16(a,b,c,0,0,0);
}

// Swizzled weight layout: frag (kc,ni,lane) at Wz[(kc*512+ni*64+lane)*8+j].
// Design log: r9 LDS weights; r10 operand-swap; r11 fused mij+segsum;
// r12 reg radW; r13 node-MLP merge; r16 in-kernel fi/phi reduction (fixed in
// r17 with plane-coalesced atomics) 545->512. r18: (a) occupancy evidence
// (r15/r17 both ~25% => 2 blocks/CU regardless of 51-53KB LDS) => spend LDS
// on PING-PONG sW buffers -> 1 barrier/phase instead of 2, preload covered
// by a full mfma phase; (b) fi/phi reductions are wave-local (own sH rows,
// same-wave LDS ordering) -> their barriers removed.
// r8 lesson: smaller edge tiles double chip-wide weight traffic.
// r6 lesson: never force min-waves that cap VGPR below live state.

struct WPtrs { const float* p[11]; };

// ===========================================================================
// Combined per-layer MLP dispatch.
//  blocks [0, nodeB):   R- and u-MLPs on xi (64 rows/block, 4 indep waves)
//  blocks [nodeB, ...): edge MLPs on mij (128 edges/block) + wave-local
//                       segment reduction of ef*dir -> fi planes, ephi -> phi.
// ===========================================================================
template<bool WITH_R>
__global__ __launch_bounds__(256,2) void mlp_layer(
    int nodeB,
    const __bf16* __restrict__ mij,
    const int*    __restrict__ esrc, const float* __restrict__ dirv,
    const __bf16* __restrict__ fW1z, const float* __restrict__ fb1,
    const __bf16* __restrict__ fW2z, const float* __restrict__ fb2,
    const __bf16* __restrict__ FW1z, const float* __restrict__ Fb1,
    const float*  __restrict__ FW2v, const float* __restrict__ Fb2,
    const __bf16* __restrict__ rW1z, const float* __restrict__ rb1,
    const __bf16* __restrict__ rW2z, const float* __restrict__ rb2,
    const float*  __restrict__ swv,
    float* __restrict__ fiG, float* __restrict__ phiG,
    const float* __restrict__ X,
    const __bf16* __restrict__ RW1z, const float* __restrict__ Rb1,
    const __bf16* __restrict__ RW2z, const float* __restrict__ Rb2,
    const __bf16* __restrict__ uW1z, const float* __restrict__ ub1,
    const __bf16* __restrict__ uW2z, const float* __restrict__ ub2,
    float* __restrict__ Rv, float* __restrict__ uv)
{
  __shared__ __bf16 sH[128*LDT];   // 34816 B
  __shared__ __bf16 sW[2][8192];   // 32768 B (ping-pong)
  __shared__ int    sE[128];       //   512 B
  __shared__ float  sDir[128*3];   //  1536 B  (total 69632 -> 2 blocks/CU)
  const int tid=threadIdx.x, lane=tid&63, wv=tid>>6, l15=lane&15, quad=lane>>4;

  if ((int)blockIdx.x < nodeB){
    // ---------------- node path: R and u MLPs, 16 rows per wave -----------
    const long row0n = (long)blockIdx.x*64 + wv*16;
    const long rA = row0n + l15;
    const bool okA = rA < N_NODES;

    bf16x8 fa[4];
    #pragma unroll
    for (int kc=0;kc<4;kc++){
      int kb=kc*32+quad*8;
      bf16x8 a;
      #pragma unroll
      for (int i=0;i<8;i++) a[i]=(__bf16)0.f;
      if (okA){
        float4 u0 = *(const float4*)(X + rA*DIM + kb);
        float4 u1 = *(const float4*)(X + rA*DIM + kb + 4);
        a[0]=(__bf16)u0.x;a[1]=(__bf16)u0.y;a[2]=(__bf16)u0.z;a[3]=(__bf16)u0.w;
        a[4]=(__bf16)u1.x;a[5]=(__bf16)u1.y;a[6]=(__bf16)u1.z;a[7]=(__bf16)u1.w;
      }
      fa[kc]=a;
    }

    f32x4 acc[8];
    auto zacc = [&](){
      #pragma unroll
      for (int ni=0;ni<8;++ni) acc[ni]=(f32x4){0.f,0.f,0.f,0.f};
    };
    auto gemmA = [&](const __bf16* __restrict__ Wz){
      #pragma unroll
      for (int kc=0;kc<4;kc++){
        #pragma unroll
        for (int ni=0;ni<8;ni++){
          bf16x8 w = *(const bf16x8*)(Wz + (long)(kc*512 + ni*64 + lane)*8);
          acc[ni]=mfma16(w,fa[kc],acc[ni]);
        }
      }
    };
    auto gemmH = [&](const __bf16* __restrict__ Wz){
      #pragma unroll
      for (int kc=0;kc<4;kc++){
        bf16x8 h0=*(bf16x8*)&sH[(wv*16+l15)*LDT + kc*32 + quad*8];
        #pragma unroll
        for (int ni=0;ni<8;ni++){
          bf16x8 w = *(const bf16x8*)(Wz + (long)(kc*512 + ni*64 + lane)*8);
          acc[ni]=mfma16(w,h0,acc[ni]);
        }
      }
    };
    auto hEpi = [&](const float* __restrict__ b1){
      #pragma unroll
      for (int ni=0;ni<8;++ni){
        int n0 = ni*16 + quad*4;
        float4 bb = *(const float4*)(b1 + n0);
        bf16x4 h;
        h[0]=(__bf16)silu_f(acc[ni][0]+bb.x);
        h[1]=(__bf16)silu_f(acc[ni][1]+bb.y);
        h[2]=(__bf16)silu_f(acc[ni][2]+bb.z);
        h[3]=(__bf16)silu_f(acc[ni][3]+bb.w);
        *(bf16x4*)&sH[(wv*16+l15)*LDT + n0] = h;
      }
    };
    auto cStoreF = [&](const float* __restrict__ b2, float* __restrict__ Y){
      if (okA){
        #pragma unroll
        for (int ni=0;ni<8;++ni){
          int n0 = ni*16 + quad*4;
          float4 bb = *(const float4*)(b2 + n0);
          float4 o;
          o.x=acc[ni][0]+bb.x; o.y=acc[ni][1]+bb.y;
          o.z=acc[ni][2]+bb.z; o.w=acc[ni][3]+bb.w;
          *(float4*)(Y + rA*DIM + n0) = o;
        }
      }
    };

    zacc(); gemmA(RW1z); hEpi(Rb1);
    zacc(); gemmH(RW2z); cStoreF(Rb2, Rv);
    zacc(); gemmA(uW1z); hEpi(ub1);
    zacc(); gemmH(uW2z); cStoreF(ub2, uv);
    return;
  }

  // ---------------- edge path: F/f[/r] MLPs on mij ------------------------
  const long row0 = (long)(blockIdx.x - nodeB)*128;
  const int  rloc0 = wv*32 + l15;
  const long rB0 = row0 + rloc0, rB1 = rB0+16;

  // stage esrc + dir for this block's 128 edges (published by first barrier)
  if (tid < 32)  *(int4*)&sE[tid*4]    = *(const int4*)(esrc + row0 + tid*4);
  if (tid >= 64 && tid < 160)
    *(float4*)&sDir[(tid-64)*4] = *(const float4*)(dirv + row0*3 + (tid-64)*4);

  bf16x8 fb[2][4];
  #pragma unroll
  for (int kc=0;kc<4;kc++){
    fb[0][kc] = *(const bf16x8*)(mij + rB0*DIM + kc*32 + quad*8);
    fb[1][kc] = *(const bf16x8*)(mij + rB1*DIM + kc*32 + quad*8);
  }
  float swr[2];
  if constexpr (WITH_R){ swr[0]=swv[rB0]; swr[1]=swv[rB1]; }

  f32x4 acc[2][8];
  bf16x8 pre[4];
  float eF[2];

  auto preload = [&](const __bf16* __restrict__ Wz, int half){
    #pragma unroll
    for (int it=0; it<4; ++it)
      pre[it] = *(const bf16x8*)(Wz + (long)(half*1024 + it*256 + tid)*8);
  };
  auto writePre = [&](int b){
    #pragma unroll
    for (int it=0; it<4; ++it)
      *(bf16x8*)&sW[b][(it*256+tid)*8] = pre[it];
  };
  auto zacc = [&](){
    #pragma unroll
    for (int mi=0;mi<2;++mi)
      #pragma unroll
      for (int ni=0;ni<8;++ni) acc[mi][ni]=(f32x4){0.f,0.f,0.f,0.f};
  };
  auto mfmaB = [&](int b, int half){
    #pragma unroll
    for (int k2=0;k2<2;k2++){
      int kc = half*2 + k2;
      #pragma unroll
      for (int ni=0;ni<8;ni++){
        bf16x8 w = *(bf16x8*)&sW[b][(k2*512 + ni*64 + lane)*8];
        acc[0][ni]=mfma16(w,fb[0][kc],acc[0][ni]);
        acc[1][ni]=mfma16(w,fb[1][kc],acc[1][ni]);
      }
    }
  };
  auto mfmaH = [&](int b, int half){
    #pragma unroll
    for (int k2=0;k2<2;k2++){
      int kc = half*2 + k2;
      bf16x8 h0=*(bf16x8*)&sH[(rloc0   )*LDT + kc*32 + quad*8];
      bf16x8 h1=*(bf16x8*)&sH[(rloc0+16)*LDT + kc*32 + quad*8];
      #pragma unroll
      for (int ni=0;ni<8;ni++){
        bf16x8 w = *(bf16x8*)&sW[b][(k2*512 + ni*64 + lane)*8];
        acc[0][ni]=mfma16(w,h0,acc[0][ni]);
        acc[1][ni]=mfma16(w,h1,acc[1][ni]);
      }
    }
  };
  auto fEpi = [&](){
    float fb2v = Fb2[0];
    #pragma unroll
    for (int mi=0;mi<2;++mi){
      float p = 0.f;
      #pragma unroll
      for (int ni=0;ni<8;++ni){
        int n0 = ni*16 + quad*4;
        float4 bb = *(const float4*)(Fb1 + n0);
        float4 w2 = *(const float4*)(FW2v + n0);
        p += silu_f(acc[mi][ni][0]+bb.x)*w2.x;
        p += silu_f(acc[mi][ni][1]+bb.y)*w2.y;
        p += silu_f(acc[mi][ni][2]+bb.z)*w2.z;
        p += silu_f(acc[mi][ni][3]+bb.w)*w2.w;
      }
      p += __shfl_xor(p,16);
      p += __shfl_xor(p,32);
      eF[mi] = p + fb2v;
    }
  };
  auto hEpi = [&](const float* __restrict__ b1){
    #pragma unroll
    for (int mi=0;mi<2;++mi){
      int rl = wv*32 + mi*16 + l15;
      #pragma unroll
      for (int ni=0;ni<8;++ni){
        int n0 = ni*16 + quad*4;
        float4 bb = *(const float4*)(b1 + n0);
        bf16x4 h;
        h[0]=(__bf16)silu_f(acc[mi][ni][0]+bb.x);
        h[1]=(__bf16)silu_f(acc[mi][ni][1]+bb.y);
        h[2]=(__bf16)silu_f(acc[mi][ni][2]+bb.z);
        h[3]=(__bf16)silu_f(acc[mi][ni][3]+bb.w);
        *(bf16x4*)&sH[rl*LDT + n0] = h;
      }
    }
  };
  // MLP output (x bias x mul) -> sH (wave-private rows), bf16
  auto outLDS = [&](const float* __restrict__ b2, const float* mul){
    #pragma unroll
    for (int mi=0;mi<2;++mi){
      int rl = wv*32 + mi*16 + l15;
      #pragma unroll
      for (int ni=0;ni<8;++ni){
        int n0 = ni*16 + quad*4;
        float4 bb = *(const float4*)(b2 + n0);
        bf16x4 o;
        o[0]=(__bf16)((acc[mi][ni][0]+bb.x)*mul[mi]);
        o[1]=(__bf16)((acc[mi][ni][1]+bb.y)*mul[mi]);
        o[2]=(__bf16)((acc[mi][ni][2]+bb.z)*mul[mi]);
        o[3]=(__bf16)((acc[mi][ni][3]+bb.w)*mul[mi]);
        *(bf16x4*)&sH[rl*LDT + n0] = o;
      }
    }
  };
  // wave wv reduces its OWN edges [32wv,32wv+32) over all 128 cols.
  // Same-wave LDS write->read ordering (lgkmcnt) -- no barrier needed.
  auto reduceFi = [&](){
    const int d = lane*2;
    float a0=0.f,a1=0.f,a2=0.f,a3=0.f,a4=0.f,a5=0.f;
    int cur = sE[wv*32];
    for (int i=0;i<32;i++){
      int e = wv*32+i;
      int n = sE[e];
      if (n != cur){                    // wave-uniform
        long b = (long)cur*DIM + d;
        atomicAdd(&fiG[0L*NFE + b  ], a0);
        atomicAdd(&fiG[0L*NFE + b+1], a3);
        atomicAdd(&fiG[1L*NFE + b  ], a1);
        atomicAdd(&fiG[1L*NFE + b+1], a4);
        atomicAdd(&fiG[2L*NFE + b  ], a2);
        atomicAdd(&fiG[2L*NFE + b+1], a5);
        a0=a1=a2=a3=a4=a5=0.f; cur=n;
      }
      bf16x2 v = *(bf16x2*)&sH[e*LDT + d];
      float vx=(float)v[0], vy=(float)v[1];
      float d0=sDir[e*3+0], d1=sDir[e*3+1], d2=sDir[e*3+2];
      a0+=vx*d0; a1+=vx*d1; a2+=vx*d2;
      a3+=vy*d0; a4+=vy*d1; a5+=vy*d2;
    }
    long b = (long)cur*DIM + d;
    atomicAdd(&fiG[0L*NFE + b  ], a0);
    atomicAdd(&fiG[0L*NFE + b+1], a3);
    atomicAdd(&fiG[1L*NFE + b  ], a1);
    atomicAdd(&fiG[1L*NFE + b+1], a4);
    atomicAdd(&fiG[2L*NFE + b  ], a2);
    atomicAdd(&fiG[2L*NFE + b+1], a5);
  };
  auto reducePhi = [&](){
    const int d = lane*2;
    float a0=0.f,a1=0.f;
    int cur = sE[wv*32];
    for (int i=0;i<32;i++){
      int e = wv*32+i;
      int n = sE[e];
      if (n != cur){
        atomicAdd(&phiG[(long)cur*DIM + d  ], a0);
        atomicAdd(&phiG[(long)cur*DIM + d+1], a1);
        a0=a1=0.f; cur=n;
      }
      bf16x2 v = *(bf16x2*)&sH[e*LDT + d];
      a0 += (float)v[0]; a1 += (float)v[1];
    }
    atomicAdd(&phiG[(long)cur*DIM + d  ], a0);
    atomicAdd(&phiG[(long)cur*DIM + d+1], a1);
  };

  // ------- ping-pong pipeline: 1 barrier per phase (publish next buf) ------
  preload(FW1z,0); writePre(0);
  __syncthreads();                  // B0 + sE/sDir published
  preload(FW1z,1);
  zacc(); mfmaB(0,0);
  writePre(1);
  __syncthreads();                  // B1 published
  preload(fW1z,0);
  mfmaB(1,1);
  writePre(0);
  __syncthreads();
  preload(fW1z,1);
  fEpi();
  zacc(); mfmaB(0,0);
  writePre(1);
  __syncthreads();
  preload(fW2z,0);
  mfmaB(1,1);
  writePre(0);
  __syncthreads();
  preload(fW2z,1);
  hEpi(fb1);
  zacc(); mfmaH(0,0);
  writePre(1);
  __syncthreads();
  if constexpr (WITH_R) preload(rW1z,0);
  mfmaH(1,1);
  outLDS(fb2, eF);                  // ef -> own sH rows
  reduceFi();                       // wave-local: fi += ef*dir

  if constexpr (WITH_R){
    writePre(0);
    __syncthreads();
    preload(rW1z,1);
    zacc(); mfmaB(0,0);
    writePre(1);
    __syncthreads();
    preload(rW2z,0);
    mfmaB(1,1);
    writePre(0);
    __syncthreads();
    preload(rW2z,1);
    hEpi(rb1);
    zacc(); mfmaH(0,0);
    writePre(1);
    __syncthreads();
    mfmaH(1,1);
    outLDS(rb2, swr);               // ephi -> own sH rows
    reducePhi();                    // wave-local: phi += ephi
  }
}

// ===========================================================================
// Node MLP a: 1-wave blocks, 16 rows each -> 625 blocks. Exact fit.
// ===========================================================================
__global__ __launch_bounds__(64,4) void mlp_a(
    const float* __restrict__ X,
    const __bf16* __restrict__ W1z, const float* __restrict__ b1,
    const __bf16* __restrict__ W2z, const float* __restrict__ b2,
    __bf16* __restrict__ Y)
{
  __shared__ __bf16 sH[16*LDT];
  const int lane=threadIdx.x, l15=lane&15, quad=lane>>4;
  const long row0=(long)blockIdx.x*16;
  const long rA=row0+l15;

  bf16x8 fa[4];
  #pragma unroll
  for (int kc=0;kc<4;kc++){
    int kb=kc*32+quad*8;
    float4 u0 = *(const float4*)(X + rA*DIM + kb);
    float4 u1 = *(const float4*)(X + rA*DIM + kb + 4);
    bf16x8 a;
    a[0]=(__bf16)u0.x;a[1]=(__bf16)u0.y;a[2]=(__bf16)u0.z;a[3]=(__bf16)u0.w;
    a[4]=(__bf16)u1.x;a[5]=(__bf16)u1.y;a[6]=(__bf16)u1.z;a[7]=(__bf16)u1.w;
    fa[kc]=a;
  }

  f32x4 acc[8];
  #pragma unroll
  for (int ni=0;ni<8;++ni) acc[ni]=(f32x4){0.f,0.f,0.f,0.f};
  #pragma unroll
  for (int kc=0;kc<4;kc++){
    #pragma unroll
    for (int ni=0;ni<8;ni++){
      bf16x8 w = *(const bf16x8*)(W1z + (long)(kc*512 + ni*64 + lane)*8);
      acc[ni]=mfma16(w,fa[kc],acc[ni]);
    }
  }
  #pragma unroll
  for (int ni=0;ni<8;++ni){
    int n0 = ni*16 + quad*4;
    float4 bb = *(const float4*)(b1 + n0);
    bf16x4 h;
    h[0]=(__bf16)silu_f(acc[ni][0]+bb.x);
    h[1]=(__bf16)silu_f(acc[ni][1]+bb.y);
    h[2]=(__bf16)silu_f(acc[ni][2]+bb.z);
    h[3]=(__bf16)silu_f(acc[ni][3]+bb.w);
    *(bf16x4*)&sH[l15*LDT + n0] = h;
  }
  #pragma unroll
  for (int ni=0;ni<8;++ni) acc[ni]=(f32x4){0.f,0.f,0.f,0.f};
  #pragma unroll
  for (int kc=0;kc<4;kc++){
    bf16x8 h0=*(bf16x8*)&sH[l15*LDT + kc*32 + quad*8];
    #pragma unroll
    for (int ni=0;ni<8;ni++){
      bf16x8 w = *(const bf16x8*)(W2z + (long)(kc*512 + ni*64 + lane)*8);
      acc[ni]=mfma16(w,h0,acc[ni]);
    }
  }
  #pragma unroll
  for (int ni=0;ni<8;++ni){
    int n0 = ni*16 + quad*4;
    float4 bb = *(const float4*)(b2 + n0);
    bf16x4 o;
    o[0]=(__bf16)(acc[ni][0]+bb.x);
    o[1]=(__bf16)(acc[ni][1]+bb.y);
    o[2]=(__bf16)(acc[ni][2]+bb.z);
    o[3]=(__bf16)(acc[ni][3]+bb.w);
    *(bf16x4*)(Y + rA*DIM + n0) = o;
  }
}

// ===========================================================================
// One-shot setup: weight swizzle + node init + edge geometry
// ===========================================================================
__global__ __launch_bounds__(256) void setup_all(
    WPtrs wp, __bf16* __restrict__ wt,
    const int* __restrict__ species, const float* __restrict__ spW,
    const float* __restrict__ spB, float* __restrict__ xi, float* __restrict__ fi,
    float* __restrict__ phi,
    const float* __restrict__ dist, const float* __restrict__ vec,
    const float* __restrict__ swv, float* __restrict__ dir, float* __restrict__ rb)
{
  const int b = blockIdx.x, tid = threadIdx.x;
  if (b < 33){
    int t = b/3, l = b%3;
    const float* src = wp.p[t] + (size_t)l*16384;
    __bf16* out = wt + (size_t)b*16384;
    for (int it=0; it<8; ++it){
      int fi_ = it*256 + tid;
      int kc = fi_>>9, ni = (fi_>>6)&7, lane = fi_&63;
      int n  = ni*16 + (lane&15);
      int k0 = kc*32 + (lane>>4)*8;
      bf16x8 v;
      #pragma unroll
      for (int j=0;j<8;++j) v[j] = (__bf16)src[(k0+j)*DIM + n];
      *(bf16x8*)(out + (size_t)fi_*8) = v;
    }
  } else if (b < 33 + 5000){
    int idx = (b-33)*256 + tid;     // < N*128
    int n = idx >> 7, d = idx & 127;
    xi[idx] = spW[species[n]*DIM + d] + spB[d];
    phi[idx] = 0.f;
    fi[idx] = 0.f;                  // plane 0
    fi[NFE + idx] = 0.f;            // plane 1
    fi[2L*NFE + idx] = 0.f;         // plane 2
  } else {
    int e = (b-5033)*256 + tid;
    if (e < N_EDGES){
      float d = dist[e];
      float s = swv[e];
      float inv = s / d;
      dir[e*3+0] = vec[e*3+0]*inv;
      dir[e*3+1] = vec[e*3+1]*inv;
      dir[e*3+2] = vec[e*3+2]*inv;
      const float eta = (16.0f/5.0f)*(16.0f/5.0f);
      #pragma unroll
      for (int j=0;j<NBASIS;j++){
        float c = (float)j * (5.0f/15.0f);
        float t2 = d - c;
        rb[e*NBASIS + j] = __expf(-eta*t2*t2);
      }
    }
  }
}

// mij = ai[src]*ai[dst]*(rb@radW + radB)*sw  AND  xi += segsum(mij).
// 64 edges/block, wave wv owns edges [16wv,16wv+16). radW cols in regs.
__global__ __launch_bounds__(256) void mij_segsum(
    const __bf16* __restrict__ ai, const int* __restrict__ esrc, const int* __restrict__ edst,
    const float* __restrict__ swv, const float* __restrict__ rb,
    const float* __restrict__ radW, const float* __restrict__ radB,
    __bf16* __restrict__ mij, float* __restrict__ xi)
{
  __shared__ float sRb[64*NBASIS];
  __shared__ int   sS[64], sD[64];
  __shared__ float sSw[64];
  int tid = threadIdx.x;
  int e0 = blockIdx.x * 64;
  *(float4*)(sRb + tid*4) = *(const float4*)(rb + (long)e0*NBASIS + tid*4);
  if (tid < 64){
    sS[tid]  = esrc[e0+tid];
    sD[tid]  = edst[e0+tid];
    sSw[tid] = swv[e0+tid];
  }
  const int wv = tid>>6, lane = tid&63;
  const int d = lane*2;
  float2 rw[NBASIS];
  #pragma unroll
  for (int j=0;j<NBASIS;j++)
    rw[j] = *(const float2*)(radW + j*DIM + d);
  float2 rB = *(const float2*)(radB + d);
  __syncthreads();

  float sx=0.f, sy=0.f;
  int cur = sS[wv*16];
  #pragma unroll
  for (int i=0;i<16;i++){
    int el = wv*16 + i;
    int n = sS[el];
    if (n != cur){                       // wave-uniform branch
      atomicAdd(&xi[(long)cur*DIM+d  ], sx);
      atomicAdd(&xi[(long)cur*DIM+d+1], sy);
      sx=0.f; sy=0.f; cur=n;
    }
    bf16x2 as = *(const bf16x2*)(ai + (long)n*DIM + d);
    bf16x2 ad = *(const bf16x2*)(ai + (long)sD[el]*DIM + d);
    float acc0 = 0.f, acc1 = 0.f;
    #pragma unroll
    for (int j=0;j<NBASIS;j++){
      float rbv = sRb[el*NBASIS+j];
      acc0 += rbv*rw[j].x;
      acc1 += rbv*rw[j].y;
    }
    float sw_ = sSw[el];
    float m0 = (float)as[0]*(float)ad[0]*(acc0+rB.x)*sw_;
    float m1 = (float)as[1]*(float)ad[1]*(acc1+rB.y)*sw_;
    bf16x2 m; m[0]=(__bf16)m0; m[1]=(__bf16)m1;
    *(bf16x2*)(mij + (long)(e0+el)*DIM + d) = m;
    sx += m0; sy += m1;
  }
  atomicAdd(&xi[(long)cur*DIM+d  ], sx);
  atomicAdd(&xi[(long)cur*DIM+d+1], sy);
}

// Elementwise node update: fi/phi fully accumulated by mlp_layer (planes).
// Zeroes phi for next layer. Writes d_out on last layer.
__global__ __launch_bounds__(256) void node_update(
    const float* __restrict__ Rv, const float* __restrict__ uv,
    float* __restrict__ fi, float* __restrict__ di, float* __restrict__ xi,
    float* __restrict__ phi, float* __restrict__ out, int layer)
{
  long idx = (long)blockIdx.x*256 + threadIdx.x;   // < N*128
  float f0 = fi[idx];
  float f1 = fi[NFE + idx];
  float f2 = fi[2L*NFE + idx];
  float phi_v = (layer > 0) ? phi[idx] : 0.f;
  float Rv_ = Rv[idx];
  float fv[3] = {f0,f1,f2};
  float sc = 0.f;
  #pragma unroll
  for (int k=0;k<3;k++){
    float delta = Rv_*fv[k];
    float dv = (layer==0) ? delta : phi_v*di[(long)k*NFE + idx] + delta;
    di[(long)k*NFE + idx] = dv;
    sc += fv[k]*dv;
  }
  float nx = xi[idx] - uv[idx]*sc;
  xi[idx] = nx;
  phi[idx] = 0.f;                 // ready for next layer's accumulation
  if (layer == 2) out[idx] = nx;
}

extern "C" void kernel_launch(void* const* d_in, const int* in_sizes, int n_in,
                              void* d_out, int out_size, void* d_ws, size_t ws_size,
                              hipStream_t stream) {
  const int*   species = (const int*)  d_in[0];
  const int*   esrc    = (const int*)  d_in[1];
  const int*   edst    = (const int*)  d_in[2];
  const float* dist    = (const float*)d_in[3];
  const float* vec     = (const float*)d_in[4];
  const float* swv     = (const float*)d_in[5];
  const float* spW     = (const float*)d_in[6];
  const float* spB     = (const float*)d_in[7];
  const float* radW    = (const float*)d_in[8];
  const float* radB    = (const float*)d_in[9];
  const float* aW1=(const float*)d_in[10], *aB1=(const float*)d_in[11], *aW2=(const float*)d_in[12], *aB2=(const float*)d_in[13];
  const float* FW1=(const float*)d_in[14], *FB1=(const float*)d_in[15], *FW2=(const float*)d_in[16], *FB2=(const float*)d_in[17];
  const float* fW1=(const float*)d_in[18], *fB1=(const float*)d_in[19], *fW2=(const float*)d_in[20], *fB2=(const float*)d_in[21];
  const float* RW1=(const float*)d_in[22], *RB1=(const float*)d_in[23], *RW2=(const float*)d_in[24], *RB2=(const float*)d_in[25];
  const float* rW1=(const float*)d_in[26], *rB1=(const float*)d_in[27], *rW2=(const float*)d_in[28], *rB2=(const float*)d_in[29];
  const float* uW1=(const float*)d_in[30], *uB1=(const float*)d_in[31], *uW2=(const float*)d_in[32], *uB2=(const float*)d_in[33];

  const long NF = (long)N_NODES*DIM;      // 1,280,000
  const long EF = (long)N_EDGES*DIM;      // 20,480,000
  float* ws   = (float*)d_ws;
  float* xi   = ws;
  float* Rv   = xi   + NF;
  float* uv   = Rv   + NF;
  float* phi  = uv   + NF;
  float* fi   = phi  + NF;                // 3 planes of NF
  float* di   = fi   + 3*NF;              // 3 planes of NF
  float* dir  = di   + 3*NF;
  float* rb   = dir  + 3L*N_EDGES;
  char* bp = (char*)(rb + 16L*N_EDGES);
  size_t off = ((size_t)(bp - (char*)d_ws) + 15) & ~(size_t)15;
  __bf16* ai   = (__bf16*)((char*)d_ws + off);
  __bf16* mij  = ai  + NF;
  __bf16* wt   = mij + EF;                // 33 x 128x128 bf16 (swizzled)

  // swizzled bf16 weights: tensor order a1,a2,F1,f1,f2,R1,R2,r1,r2,u1,u2
  WPtrs wp;
  wp.p[0]=aW1; wp.p[1]=aW2; wp.p[2]=FW1; wp.p[3]=fW1; wp.p[4]=fW2;
  wp.p[5]=RW1; wp.p[6]=RW2; wp.p[7]=rW1; wp.p[8]=rW2; wp.p[9]=uW1; wp.p[10]=uW2;

  // one-shot setup: 33 convert + 5000 init + 625 geom = 5658 blocks
  setup_all<<<5658, 256, 0, stream>>>(wp, wt,
                                      species, spW, spB, xi, fi, phi,
                                      dist, vec, swv, dir, rb);

  const int nodeB = (N_NODES + 63)/64;        // 157 (node part of mlp_layer)
  const int edgeB = N_EDGES/128;              // 1250
  #define WT(t,l) (wt + (size_t)((t)*3+(l))*16384)

  for (int l=0;l<3;l++){
    const long bo = (long)l*DIM;

    // ai = mlp_a(xi)
    mlp_a<<<N_NODES/16, 64, 0, stream>>>(xi, WT(0,l), aB1+bo, WT(1,l), aB2+bo, ai);
    // mij (bf16) + xi += segsum(mij)   [fused, atomics]
    mij_segsum<<<N_EDGES/64, 256, 0, stream>>>(ai, esrc, edst, swv, rb,
                                               radW + (long)l*NBASIS*DIM, radB + bo,
                                               mij, xi);
    // combined: [node] Rv,uv  +  [edge] f/F[/r] MLPs with wave-local
    // fi/phi segment reductions (no ef/ephi in HBM; plane-coalesced atomics)
    if (l == 0)
      mlp_layer<false><<<nodeB+edgeB, 256, 0, stream>>>(
          nodeB, mij, esrc, dir,
          WT(3,l), fB1+bo, WT(4,l), fB2+bo,
          WT(2,l), FB1+bo, FW2+(long)l*DIM, FB2+l,
          nullptr, nullptr, nullptr, nullptr, nullptr,
          fi, phi,
          xi, WT(5,l), RB1+bo, WT(6,l), RB2+bo,
          WT(9,l), uB1+bo, WT(10,l), uB2+bo, Rv, uv);
    else
      mlp_layer<true><<<nodeB+edgeB, 256, 0, stream>>>(
          nodeB, mij, esrc, dir,
          WT(3,l), fB1+bo, WT(4,l), fB2+bo,
          WT(2,l), FB1+bo, FW2+(long)l*DIM, FB2+l,
          WT(7,l), rB1+bo, WT(8,l), rB2+bo, swv,
          fi, phi,
          xi, WT(5,l), RB1+bo, WT(6,l), RB2+bo,
          WT(9,l), uB1+bo, WT(10,l), uB2+bo, Rv, uv);
    // di, scal, xi (+ d_out on last layer); zeroes phi for next layer
    node_update<<<5000, 256, 0, stream>>>(Rv, uv, fi, di, xi, phi,
                                          (float*)d_out, l);
  }
}